// Round 1
// baseline (2634.460 us; speedup 1.0000x reference)
//
#include <hip/hip_runtime.h>
#include <math.h>

#define EMB 512
#define NH 8
#define HD 64
#define BB 2
#define SS 1024
#define ROWS (BB * SS) /* 2048 */

// ============================================================
// Kernel 1a: projections  C = f_emb[2048x512] @ [Wu|Wq|Wkv][512x2048]
// fused epilogue: bias + attention-biases + tanh -> 6 activation arrays
// ============================================================
__global__ __launch_bounds__(256) void proj_gemm_kernel(
    const float* __restrict__ A, const float* __restrict__ Wu,
    const float* __restrict__ Wu_b, const float* __restrict__ Wq,
    const float* __restrict__ Wq_b, const float* __restrict__ Wkv,
    const float* __restrict__ Wkv_b, const float* __restrict__ Buc,
    const float* __restrict__ Bup, const float* __restrict__ Bfc,
    const float* __restrict__ Bfp, float* __restrict__ qcU,
    float* __restrict__ qpU, float* __restrict__ qcF, float* __restrict__ qpF,
    float* __restrict__ khO, float* __restrict__ vhO) {
  const int tid = threadIdx.x;
  const int cb = blockIdx.x * 64;  // global column in [0,2048)
  const int mb = blockIdx.y * 64;

  const float* W;
  int ldw, coff;
  if (cb < 512) {
    W = Wu; ldw = 512; coff = cb;
  } else if (cb < 1024) {
    W = Wq; ldw = 512; coff = cb - 512;
  } else {
    W = Wkv; ldw = 1024; coff = cb - 1024;
  }

  __shared__ __align__(16) float As[16][64];
  __shared__ __align__(16) float Bs[16][64];

  const int tx = tid & 15, ty = tid >> 4;
  const int lm = tid >> 2, lk = (tid & 3) << 2;   // A loader: m, k4
  const int bk = tid >> 4, bn = (tid & 15) << 2;  // B loader: k, n4

  float acc[4][4];
#pragma unroll
  for (int i = 0; i < 4; ++i)
#pragma unroll
    for (int jj = 0; jj < 4; ++jj) acc[i][jj] = 0.f;

  for (int k0 = 0; k0 < 512; k0 += 16) {
    const float4 av = *(const float4*)&A[(size_t)(mb + lm) * 512 + k0 + lk];
    const float4 bv = *(const float4*)&W[(size_t)(k0 + bk) * ldw + coff + bn];
    __syncthreads();
    As[lk + 0][lm] = av.x;
    As[lk + 1][lm] = av.y;
    As[lk + 2][lm] = av.z;
    As[lk + 3][lm] = av.w;
    *(float4*)&Bs[bk][bn] = bv;
    __syncthreads();
#pragma unroll
    for (int kk = 0; kk < 16; ++kk) {
      const float4 a = *(const float4*)&As[kk][ty * 4];
      const float4 b = *(const float4*)&Bs[kk][tx * 4];
      acc[0][0] += a.x * b.x; acc[0][1] += a.x * b.y;
      acc[0][2] += a.x * b.z; acc[0][3] += a.x * b.w;
      acc[1][0] += a.y * b.x; acc[1][1] += a.y * b.y;
      acc[1][2] += a.y * b.z; acc[1][3] += a.y * b.w;
      acc[2][0] += a.z * b.x; acc[2][1] += a.z * b.y;
      acc[2][2] += a.z * b.z; acc[2][3] += a.z * b.w;
      acc[3][0] += a.w * b.x; acc[3][1] += a.w * b.y;
      acc[3][2] += a.w * b.z; acc[3][3] += a.w * b.w;
    }
  }

#pragma unroll
  for (int i = 0; i < 4; ++i) {
    const int row = mb + ty * 4 + i;
#pragma unroll
    for (int jj = 0; jj < 4; ++jj) {
      const int cc = coff + tx * 4 + jj;  // column within selected weight
      const float v = acc[i][jj];
      if (cb < 512) {
        const float q = v + Wu_b[cc];
        qcU[(size_t)row * 512 + cc] = tanhf(q + Buc[cc]);
        qpU[(size_t)row * 512 + cc] = tanhf(q + Bup[cc]);
      } else if (cb < 1024) {
        const float q = v + Wq_b[cc];
        qcF[(size_t)row * 512 + cc] = tanhf(q + Bfc[cc]);
        qpF[(size_t)row * 512 + cc] = tanhf(q + Bfp[cc]);
      } else if (cb < 1536) {
        khO[(size_t)row * 512 + cc] = tanhf(v + Wkv_b[cc]);
      } else {
        vhO[(size_t)row * 512 + (cc - 512)] = tanhf(v + Wkv_b[cc]);
      }
    }
  }
}

// ============================================================
// Kernel 1b: kp = tanh(gpe[2048x128] @ Wp[128x512] + Wp_b)
// ============================================================
__global__ __launch_bounds__(256) void pe_gemm_kernel(
    const float* __restrict__ A, const float* __restrict__ Wp,
    const float* __restrict__ Wp_b, float* __restrict__ kpO) {
  const int tid = threadIdx.x;
  const int cb = blockIdx.x * 64;  // [0,512)
  const int mb = blockIdx.y * 64;

  __shared__ __align__(16) float As[16][64];
  __shared__ __align__(16) float Bs[16][64];

  const int tx = tid & 15, ty = tid >> 4;
  const int lm = tid >> 2, lk = (tid & 3) << 2;
  const int bk = tid >> 4, bn = (tid & 15) << 2;

  float acc[4][4];
#pragma unroll
  for (int i = 0; i < 4; ++i)
#pragma unroll
    for (int jj = 0; jj < 4; ++jj) acc[i][jj] = 0.f;

  for (int k0 = 0; k0 < 128; k0 += 16) {
    const float4 av = *(const float4*)&A[(size_t)(mb + lm) * 128 + k0 + lk];
    const float4 bv = *(const float4*)&Wp[(size_t)(k0 + bk) * 512 + cb + bn];
    __syncthreads();
    As[lk + 0][lm] = av.x;
    As[lk + 1][lm] = av.y;
    As[lk + 2][lm] = av.z;
    As[lk + 3][lm] = av.w;
    *(float4*)&Bs[bk][bn] = bv;
    __syncthreads();
#pragma unroll
    for (int kk = 0; kk < 16; ++kk) {
      const float4 a = *(const float4*)&As[kk][ty * 4];
      const float4 b = *(const float4*)&Bs[kk][tx * 4];
      acc[0][0] += a.x * b.x; acc[0][1] += a.x * b.y;
      acc[0][2] += a.x * b.z; acc[0][3] += a.x * b.w;
      acc[1][0] += a.y * b.x; acc[1][1] += a.y * b.y;
      acc[1][2] += a.y * b.z; acc[1][3] += a.y * b.w;
      acc[2][0] += a.z * b.x; acc[2][1] += a.z * b.y;
      acc[2][2] += a.z * b.z; acc[2][3] += a.z * b.w;
      acc[3][0] += a.w * b.x; acc[3][1] += a.w * b.y;
      acc[3][2] += a.w * b.z; acc[3][3] += a.w * b.w;
    }
  }

#pragma unroll
  for (int i = 0; i < 4; ++i) {
    const int row = mb + ty * 4 + i;
#pragma unroll
    for (int jj = 0; jj < 4; ++jj) {
      const int c = cb + tx * 4 + jj;
      kpO[(size_t)row * 512 + c] = tanhf(acc[i][jj] + Wp_b[c]);
    }
  }
}

// ============================================================
// Kernel 2: attention per (stream t, batch b, row j)
//   scores (ctx + rel-shifted pos) for k<=j, softmax, AV,
//   residual + layernorm epilogue.
// rel_shift: idx = b*S + j + B; b2 = idx/(S+1); j2 = idx%(S+1);
//   pos row = (j2==0) ? 0 : qp[b2][j2-1] . kp[b2][k]
// ============================================================
__global__ __launch_bounds__(256) void attn_kernel(
    const float* __restrict__ qcU, const float* __restrict__ qpU,
    const float* __restrict__ qcF, const float* __restrict__ qpF,
    const float* __restrict__ kh, const float* __restrict__ vh,
    const float* __restrict__ kp, const float* __restrict__ u_emb,
    const float* __restrict__ f_emb, float* __restrict__ out) {
  const int j = blockIdx.x;
  const int b = blockIdx.y;
  const int t = blockIdx.z;  // 0 = u stream, 1 = f stream
  const int tid = threadIdx.x;

  __shared__ __align__(16) float sQc[512];
  __shared__ __align__(16) float sQp[512];
  __shared__ float sS[8 * 1024];
  __shared__ float sPart[8][33];
  __shared__ float sMax[8], sDen[8];
  __shared__ float sRed[256], sRed2[256];

  const int idx = b * SS + j + BB;
  const int b2 = idx / (SS + 1);
  const int j2 = idx % (SS + 1);
  const bool hasPos = (j2 > 0);
  const int jp = j2 - 1;

  const float* qc = (t == 0) ? qcU : qcF;
  const float* qp = (t == 0) ? qpU : qpF;

  for (int c = tid; c < 512; c += 256) {
    sQc[c] = qc[(size_t)(b * SS + j) * 512 + c];
    sQp[c] = hasPos ? qp[(size_t)(b2 * SS + jp) * 512 + c] : 0.f;
  }
  __syncthreads();

  const int nk = j + 1;  // causal: k in [0, j]
  {
    const int n = tid & 7;
    const float4* qcn = (const float4*)&sQc[n * 64];
    const float4* qpn = (const float4*)&sQp[n * 64];
    if (hasPos) {
      for (int k = tid >> 3; k < nk; k += 32) {
        const float4* khr =
            (const float4*)&kh[((size_t)(b * SS) + k) * 512 + n * 64];
        const float4* kpr =
            (const float4*)&kp[((size_t)(b2 * SS) + k) * 512 + n * 64];
        float acc = 0.f;
#pragma unroll
        for (int d4 = 0; d4 < 16; ++d4) {
          const float4 kv = khr[d4];
          const float4 pv = kpr[d4];
          const float4 qv = qcn[d4];
          const float4 q2 = qpn[d4];
          acc += qv.x * kv.x + qv.y * kv.y + qv.z * kv.z + qv.w * kv.w;
          acc += q2.x * pv.x + q2.y * pv.y + q2.z * pv.z + q2.w * pv.w;
        }
        sS[n * 1024 + k] = acc * 0.125f;  // 1/sqrt(64)
      }
    } else {
      for (int k = tid >> 3; k < nk; k += 32) {
        const float4* khr =
            (const float4*)&kh[((size_t)(b * SS) + k) * 512 + n * 64];
        float acc = 0.f;
#pragma unroll
        for (int d4 = 0; d4 < 16; ++d4) {
          const float4 kv = khr[d4];
          const float4 qv = qcn[d4];
          acc += qv.x * kv.x + qv.y * kv.y + qv.z * kv.z + qv.w * kv.w;
        }
        sS[n * 1024 + k] = acc * 0.125f;
      }
    }
  }
  __syncthreads();

  // softmax: 32 threads per head
  {
    const int h = tid >> 5, l = tid & 31;
    float mx = -INFINITY;
    for (int k = l; k < nk; k += 32) mx = fmaxf(mx, sS[h * 1024 + k]);
    sPart[h][l] = mx;
  }
  __syncthreads();
  if (tid < 8) {
    float mx = sPart[tid][0];
    for (int l = 1; l < 32; ++l) mx = fmaxf(mx, sPart[tid][l]);
    sMax[tid] = mx;
  }
  __syncthreads();
  {
    const int h = tid >> 5, l = tid & 31;
    const float mx = sMax[h];
    float sum = 0.f;
    for (int k = l; k < nk; k += 32) {
      const float e = __expf(sS[h * 1024 + k] - mx);
      sS[h * 1024 + k] = e;
      sum += e;
    }
    sPart[h][l] = sum;
  }
  __syncthreads();
  if (tid < 8) {
    float s = 0.f;
    for (int l = 0; l < 32; ++l) s += sPart[tid][l];
    sDen[tid] = 1.f / s;
  }
  __syncthreads();

  // AV + residual
  const float* resid = (t == 0) ? u_emb : f_emb;
  float y[2];
#pragma unroll
  for (int rep = 0; rep < 2; ++rep) {
    const int o = tid + rep * 256;
    const int hn = o >> 6, d = o & 63;
    const float* pv = &sS[hn * 1024];
    const float* vcol = &vh[(size_t)(b * SS) * 512 + hn * 64 + d];
    float a0 = 0.f, a1 = 0.f, a2 = 0.f, a3 = 0.f;
    int k = 0;
    for (; k + 4 <= nk; k += 4) {
      a0 += pv[k + 0] * vcol[(size_t)(k + 0) * 512];
      a1 += pv[k + 1] * vcol[(size_t)(k + 1) * 512];
      a2 += pv[k + 2] * vcol[(size_t)(k + 2) * 512];
      a3 += pv[k + 3] * vcol[(size_t)(k + 3) * 512];
    }
    for (; k < nk; ++k) a0 += pv[k] * vcol[(size_t)k * 512];
    const float av = (a0 + a1) + (a2 + a3);
    y[rep] = resid[(size_t)(b * SS + j) * 512 + o] + av * sDen[hn];
  }

  // layernorm over the 512-wide row
  sRed[tid] = y[0] + y[1];
  sRed2[tid] = y[0] * y[0] + y[1] * y[1];
  __syncthreads();
  for (int s = 128; s > 0; s >>= 1) {
    if (tid < s) {
      sRed[tid] += sRed[tid + s];
      sRed2[tid] += sRed2[tid + s];
    }
    __syncthreads();
  }
  const float mean = sRed[0] * (1.f / 512.f);
  const float var = sRed2[0] * (1.f / 512.f) - mean * mean;
  const float rstd = rsqrtf(var + 1e-5f);

#pragma unroll
  for (int rep = 0; rep < 2; ++rep) {
    const int o = tid + rep * 256;
    out[(size_t)t * ROWS * 512 + (size_t)(b * SS + j) * 512 + o] =
        (y[rep] - mean) * rstd;
  }
}

// ============================================================
extern "C" void kernel_launch(void* const* d_in, const int* in_sizes, int n_in,
                              void* d_out, int out_size, void* d_ws,
                              size_t ws_size, hipStream_t stream) {
  (void)in_sizes; (void)n_in; (void)out_size; (void)ws_size;
  const float* u_emb = (const float*)d_in[0];
  const float* f_emb = (const float*)d_in[1];
  const float* gpe = (const float*)d_in[2];
  // d_in[3] u_mask, d_in[4] f_mask: exactly causal -> handled analytically
  const float* Wq_w = (const float*)d_in[5];
  const float* Wq_b = (const float*)d_in[6];
  const float* Wkv_w = (const float*)d_in[7];
  const float* Wkv_b = (const float*)d_in[8];
  const float* Wp_w = (const float*)d_in[9];
  const float* Wp_b = (const float*)d_in[10];
  const float* Wu_w = (const float*)d_in[11];
  const float* Wu_b = (const float*)d_in[12];
  const float* Bfc = (const float*)d_in[13];
  const float* Bfp = (const float*)d_in[14];
  const float* Buc = (const float*)d_in[15];
  const float* Bup = (const float*)d_in[16];
  float* out = (float*)d_out;

  float* ws = (float*)d_ws;
  const size_t SZ = (size_t)ROWS * EMB;  // 1048576 floats
  float* qcU = ws + 0 * SZ;
  float* qpU = ws + 1 * SZ;
  float* qcF = ws + 2 * SZ;
  float* qpF = ws + 3 * SZ;
  float* kh = ws + 4 * SZ;
  float* vh = ws + 5 * SZ;
  float* kp = ws + 6 * SZ;

  dim3 blk(256);
  dim3 g1(32, 32);  // N=2048/64, M=2048/64
  hipLaunchKernelGGL(proj_gemm_kernel, g1, blk, 0, stream, f_emb, Wu_w, Wu_b,
                     Wq_w, Wq_b, Wkv_w, Wkv_b, Buc, Bup, Bfc, Bfp, qcU, qpU,
                     qcF, qpF, kh, vh);
  dim3 g2(8, 32);  // N=512/64, M=2048/64
  hipLaunchKernelGGL(pe_gemm_kernel, g2, blk, 0, stream, gpe, Wp_w, Wp_b, kp);
  dim3 g3(SS, BB, 2);
  hipLaunchKernelGGL(attn_kernel, g3, blk, 0, stream, qcU, qpU, qcF, qpF, kh,
                     vh, kp, u_emb, f_emb, out);
}

// Round 2
// 229.347 us; speedup vs baseline: 11.4868x; 11.4868x over previous
//
#include <hip/hip_runtime.h>
#include <math.h>

#define EMB 512
#define NH 8
#define HD 64
#define BB 2
#define SS 1024
#define ROWS (BB * SS) /* 2048 */

typedef __attribute__((ext_vector_type(8))) short bhalf8;
typedef __attribute__((ext_vector_type(4))) float f32x4;
typedef unsigned short ushort_t;

__device__ __forceinline__ unsigned short f2bf(float x) {
  unsigned u = __float_as_uint(x);
  u = (u + 0x7FFFu + ((u >> 16) & 1u)) >> 16;
  return (unsigned short)u;
}

__device__ __forceinline__ float fast_tanh(float x) {
  x = fminf(15.f, fmaxf(-15.f, x));
  const float e = __expf(2.f * x);
  return (e - 1.f) / (e + 1.f);
}

// ============================================================
// Kernel 1a: projections  C = f_emb[2048x512] @ [Wu|Wq|Wkv][512x2048]
// epilogue: bias + attn-bias + tanh -> bf16 activation arrays
// ============================================================
__global__ __launch_bounds__(256) void proj_gemm_kernel(
    const float* __restrict__ A, const float* __restrict__ Wu,
    const float* __restrict__ Wu_b, const float* __restrict__ Wq,
    const float* __restrict__ Wq_b, const float* __restrict__ Wkv,
    const float* __restrict__ Wkv_b, const float* __restrict__ Buc,
    const float* __restrict__ Bup, const float* __restrict__ Bfc,
    const float* __restrict__ Bfp, ushort_t* __restrict__ qcU,
    ushort_t* __restrict__ qpU, ushort_t* __restrict__ qcF,
    ushort_t* __restrict__ qpF, ushort_t* __restrict__ khB,
    ushort_t* __restrict__ vhB) {
  const int tid = threadIdx.x;
  const int cb = blockIdx.x * 64;  // global column in [0,2048)
  const int mb = blockIdx.y * 64;

  const float* W;
  int ldw, coff;
  if (cb < 512) {
    W = Wu; ldw = 512; coff = cb;
  } else if (cb < 1024) {
    W = Wq; ldw = 512; coff = cb - 512;
  } else {
    W = Wkv; ldw = 1024; coff = cb - 1024;
  }

  __shared__ __align__(16) float As[16][64];
  __shared__ __align__(16) float Bs[16][64];

  const int tx = tid & 15, ty = tid >> 4;
  const int lm = tid >> 2, lk = (tid & 3) << 2;
  const int bk = tid >> 4, bn = (tid & 15) << 2;

  float acc[4][4];
#pragma unroll
  for (int i = 0; i < 4; ++i)
#pragma unroll
    for (int jj = 0; jj < 4; ++jj) acc[i][jj] = 0.f;

  for (int k0 = 0; k0 < 512; k0 += 16) {
    const float4 av = *(const float4*)&A[(size_t)(mb + lm) * 512 + k0 + lk];
    const float4 bv = *(const float4*)&W[(size_t)(k0 + bk) * ldw + coff + bn];
    __syncthreads();
    As[lk + 0][lm] = av.x;
    As[lk + 1][lm] = av.y;
    As[lk + 2][lm] = av.z;
    As[lk + 3][lm] = av.w;
    *(float4*)&Bs[bk][bn] = bv;
    __syncthreads();
#pragma unroll
    for (int kk = 0; kk < 16; ++kk) {
      const float4 a = *(const float4*)&As[kk][ty * 4];
      const float4 b = *(const float4*)&Bs[kk][tx * 4];
      acc[0][0] += a.x * b.x; acc[0][1] += a.x * b.y;
      acc[0][2] += a.x * b.z; acc[0][3] += a.x * b.w;
      acc[1][0] += a.y * b.x; acc[1][1] += a.y * b.y;
      acc[1][2] += a.y * b.z; acc[1][3] += a.y * b.w;
      acc[2][0] += a.z * b.x; acc[2][1] += a.z * b.y;
      acc[2][2] += a.z * b.z; acc[2][3] += a.z * b.w;
      acc[3][0] += a.w * b.x; acc[3][1] += a.w * b.y;
      acc[3][2] += a.w * b.z; acc[3][3] += a.w * b.w;
    }
  }

#pragma unroll
  for (int i = 0; i < 4; ++i) {
    const int row = mb + ty * 4 + i;
    const int c0 = tx * 4;
    if (cb < 512) {
      ushort_t o1[4], o2[4];
#pragma unroll
      for (int jj = 0; jj < 4; ++jj) {
        const int cc = cb + c0 + jj;
        const float q = acc[i][jj] + Wu_b[cc];
        o1[jj] = f2bf(fast_tanh(q + Buc[cc]));
        o2[jj] = f2bf(fast_tanh(q + Bup[cc]));
      }
      *(ushort4*)&qcU[(size_t)row * 512 + cb + c0] =
          make_ushort4(o1[0], o1[1], o1[2], o1[3]);
      *(ushort4*)&qpU[(size_t)row * 512 + cb + c0] =
          make_ushort4(o2[0], o2[1], o2[2], o2[3]);
    } else if (cb < 1024) {
      ushort_t o1[4], o2[4];
#pragma unroll
      for (int jj = 0; jj < 4; ++jj) {
        const int cc = (cb - 512) + c0 + jj;
        const float q = acc[i][jj] + Wq_b[cc];
        o1[jj] = f2bf(fast_tanh(q + Bfc[cc]));
        o2[jj] = f2bf(fast_tanh(q + Bfp[cc]));
      }
      *(ushort4*)&qcF[(size_t)row * 512 + (cb - 512) + c0] =
          make_ushort4(o1[0], o1[1], o1[2], o1[3]);
      *(ushort4*)&qpF[(size_t)row * 512 + (cb - 512) + c0] =
          make_ushort4(o2[0], o2[1], o2[2], o2[3]);
    } else {
      ushort_t o1[4];
#pragma unroll
      for (int jj = 0; jj < 4; ++jj) {
        const int cc = (cb - 1024) + c0 + jj;
        o1[jj] = f2bf(fast_tanh(acc[i][jj] + Wkv_b[cc]));
      }
      if (cb < 1536)
        *(ushort4*)&khB[(size_t)row * 512 + (cb - 1024) + c0] =
            make_ushort4(o1[0], o1[1], o1[2], o1[3]);
      else
        *(ushort4*)&vhB[(size_t)row * 512 + (cb - 1536) + c0] =
            make_ushort4(o1[0], o1[1], o1[2], o1[3]);
    }
  }
}

// ============================================================
// Kernel 1b: kp = tanh(gpe[2048x128] @ Wp[128x512] + Wp_b) -> bf16
// ============================================================
__global__ __launch_bounds__(256) void pe_gemm_kernel(
    const float* __restrict__ A, const float* __restrict__ Wp,
    const float* __restrict__ Wp_b, ushort_t* __restrict__ kpB) {
  const int tid = threadIdx.x;
  const int cb = blockIdx.x * 64;
  const int mb = blockIdx.y * 64;

  __shared__ __align__(16) float As[16][64];
  __shared__ __align__(16) float Bs[16][64];

  const int tx = tid & 15, ty = tid >> 4;
  const int lm = tid >> 2, lk = (tid & 3) << 2;
  const int bk = tid >> 4, bn = (tid & 15) << 2;

  float acc[4][4];
#pragma unroll
  for (int i = 0; i < 4; ++i)
#pragma unroll
    for (int jj = 0; jj < 4; ++jj) acc[i][jj] = 0.f;

  for (int k0 = 0; k0 < 128; k0 += 16) {
    const float4 av = *(const float4*)&A[(size_t)(mb + lm) * 128 + k0 + lk];
    const float4 bv = *(const float4*)&Wp[(size_t)(k0 + bk) * 512 + cb + bn];
    __syncthreads();
    As[lk + 0][lm] = av.x;
    As[lk + 1][lm] = av.y;
    As[lk + 2][lm] = av.z;
    As[lk + 3][lm] = av.w;
    *(float4*)&Bs[bk][bn] = bv;
    __syncthreads();
#pragma unroll
    for (int kk = 0; kk < 16; ++kk) {
      const float4 a = *(const float4*)&As[kk][ty * 4];
      const float4 b = *(const float4*)&Bs[kk][tx * 4];
      acc[0][0] += a.x * b.x; acc[0][1] += a.x * b.y;
      acc[0][2] += a.x * b.z; acc[0][3] += a.x * b.w;
      acc[1][0] += a.y * b.x; acc[1][1] += a.y * b.y;
      acc[1][2] += a.y * b.z; acc[1][3] += a.y * b.w;
      acc[2][0] += a.z * b.x; acc[2][1] += a.z * b.y;
      acc[2][2] += a.z * b.z; acc[2][3] += a.z * b.w;
      acc[3][0] += a.w * b.x; acc[3][1] += a.w * b.y;
      acc[3][2] += a.w * b.z; acc[3][3] += a.w * b.w;
    }
  }

#pragma unroll
  for (int i = 0; i < 4; ++i) {
    const int row = mb + ty * 4 + i;
    ushort_t o1[4];
#pragma unroll
    for (int jj = 0; jj < 4; ++jj) {
      const int c = cb + tx * 4 + jj;
      o1[jj] = f2bf(fast_tanh(acc[i][jj] + Wp_b[c]));
    }
    *(ushort4*)&kpB[(size_t)row * 512 + cb + tx * 4] =
        make_ushort4(o1[0], o1[1], o1[2], o1[3]);
  }
}

// ============================================================
// Kernel 2: flash-style MFMA attention.
// Block = (jt, b*8+h, t), 256 thr = 4 waves, 64 Q-rows per block,
// wave w owns rows w*16..w*16+15. Q2=[qc|qp_shift] (K=128),
// K2=[kh|kp], S=Q2@K2^T/8, online softmax, O += P@V.
// rel-shift: b=0 -> qp row j+1 (j=1023 zero); b=1 -> qp row j.
// ============================================================
__global__ __launch_bounds__(256, 3) void attn_mfma_kernel(
    const ushort_t* __restrict__ qcU, const ushort_t* __restrict__ qpU,
    const ushort_t* __restrict__ qcF, const ushort_t* __restrict__ qpF,
    const ushort_t* __restrict__ khB, const ushort_t* __restrict__ vhB,
    const ushort_t* __restrict__ kpB, float* __restrict__ attO) {
  const int jt = 15 - (int)blockIdx.x;  // heavy tiles first
  const int h = blockIdx.y & 7, b = blockIdx.y >> 3;
  const int t = blockIdx.z;
  const int tid = threadIdx.x;
  const int w = tid >> 6;
  const int lane = tid & 63;
  const int ln = lane & 15, quad = lane >> 4;

  // padded LDS: row strides chosen so b128 frag reads are <=2-way conflicts
  __shared__ __align__(16) ushort_t sQ2[64 * 136];
  __shared__ __align__(16) ushort_t sK2[64 * 136];
  __shared__ __align__(16) ushort_t sVt[64 * 72];
  __shared__ __align__(16) ushort_t sP[64 * 72];

  const ushort_t* qcS = t ? qcF : qcU;
  const ushort_t* qpS = t ? qpF : qpU;

  // ---- stage Q2 tile [64 rows][128] ----
#pragma unroll
  for (int i = 0; i < 2; ++i) {
    const int idx = tid + i * 256;  // 0..511
    const int r = idx >> 3, c = idx & 7;
    const int j = jt * 64 + r;
    const size_t qrow = (size_t)(b * SS + j);
    *(uint4*)&sQ2[r * 136 + c * 8] =
        *(const uint4*)&qcS[qrow * 512 + h * 64 + c * 8];
    uint4 qp;
    if (b == 0) {
      if (j == SS - 1)
        qp = make_uint4(0u, 0u, 0u, 0u);
      else
        qp = *(const uint4*)&qpS[(qrow + 1) * 512 + h * 64 + c * 8];
    } else {
      qp = *(const uint4*)&qpS[qrow * 512 + h * 64 + c * 8];
    }
    *(uint4*)&sQ2[r * 136 + 64 + c * 8] = qp;
  }
  __syncthreads();

  // persistent A-frags for Q2 (K=128 -> 4 chunks of 32)
  bhalf8 aq[4];
#pragma unroll
  for (int kc = 0; kc < 4; ++kc)
    aq[kc] = *(const bhalf8*)&sQ2[(w * 16 + ln) * 136 + kc * 32 + quad * 8];

  f32x4 oacc[4];
#pragma unroll
  for (int ct = 0; ct < 4; ++ct) oacc[ct] = (f32x4){0.f, 0.f, 0.f, 0.f};
  float mrun[4], lrun[4];
#pragma unroll
  for (int r = 0; r < 4; ++r) { mrun[r] = -1e30f; lrun[r] = 0.f; }

  for (int kt = 0; kt <= jt; ++kt) {
    __syncthreads();  // protect prev-iter reads of sK2/sVt
    // stage K2 [64][128]
#pragma unroll
    for (int i = 0; i < 2; ++i) {
      const int idx = tid + i * 256;
      const int r = idx >> 3, c = idx & 7;
      const size_t krow = (size_t)(b * SS + kt * 64 + r);
      *(uint4*)&sK2[r * 136 + c * 8] =
          *(const uint4*)&khB[krow * 512 + h * 64 + c * 8];
      *(uint4*)&sK2[r * 136 + 64 + c * 8] =
          *(const uint4*)&kpB[krow * 512 + h * 64 + c * 8];
    }
    // stage V transposed: sVt[d][k]
#pragma unroll
    for (int i = 0; i < 2; ++i) {
      const int idx = tid + i * 256;
      const int r = idx >> 3, dq = idx & 7;
      const size_t vrow = (size_t)(b * SS + kt * 64 + r);
      const uint4 vv = *(const uint4*)&vhB[vrow * 512 + h * 64 + dq * 8];
      unsigned va[4] = {vv.x, vv.y, vv.z, vv.w};
#pragma unroll
      for (int q2 = 0; q2 < 4; ++q2) {
        sVt[(dq * 8 + q2 * 2 + 0) * 72 + r] = (ushort_t)(va[q2] & 0xffffu);
        sVt[(dq * 8 + q2 * 2 + 1) * 72 + r] = (ushort_t)(va[q2] >> 16);
      }
    }
    __syncthreads();

    // S-tile: 16x16 subtiles, wave rows x 64 cols
    f32x4 sacc[4];
#pragma unroll
    for (int ct = 0; ct < 4; ++ct) {
      sacc[ct] = (f32x4){0.f, 0.f, 0.f, 0.f};
#pragma unroll
      for (int kc = 0; kc < 4; ++kc) {
        const bhalf8 bk =
            *(const bhalf8*)&sK2[(ct * 16 + ln) * 136 + kc * 32 + quad * 8];
        sacc[ct] =
            __builtin_amdgcn_mfma_f32_16x16x32_bf16(aq[kc], bk, sacc[ct], 0, 0, 0);
      }
    }

    // scale + causal mask (only diagonal supertile partial)
    const bool diag = (kt == jt);
#pragma unroll
    for (int ct = 0; ct < 4; ++ct)
#pragma unroll
      for (int r = 0; r < 4; ++r) {
        float v = sacc[ct][r] * 0.125f;
        if (diag && (ct * 16 + ln > w * 16 + quad * 4 + r)) v = -1e30f;
        sacc[ct][r] = v;
      }

    // online softmax (row = quad*4+r, reduce over 16 lanes of quad)
    float mnew[4], alpha[4], psum[4];
#pragma unroll
    for (int r = 0; r < 4; ++r) {
      float v = fmaxf(fmaxf(sacc[0][r], sacc[1][r]),
                      fmaxf(sacc[2][r], sacc[3][r]));
      v = fmaxf(v, __shfl_xor(v, 1));
      v = fmaxf(v, __shfl_xor(v, 2));
      v = fmaxf(v, __shfl_xor(v, 4));
      v = fmaxf(v, __shfl_xor(v, 8));
      mnew[r] = fmaxf(mrun[r], v);
      alpha[r] = __expf(mrun[r] - mnew[r]);
      mrun[r] = mnew[r];
      psum[r] = 0.f;
    }
#pragma unroll
    for (int ct = 0; ct < 4; ++ct)
#pragma unroll
      for (int r = 0; r < 4; ++r) {
        const float p = __expf(sacc[ct][r] - mnew[r]);
        sacc[ct][r] = p;
        psum[r] += p;
      }
#pragma unroll
    for (int r = 0; r < 4; ++r) {
      float s = psum[r];
      s += __shfl_xor(s, 1);
      s += __shfl_xor(s, 2);
      s += __shfl_xor(s, 4);
      s += __shfl_xor(s, 8);
      lrun[r] = lrun[r] * alpha[r] + s;
#pragma unroll
      for (int ct = 0; ct < 4; ++ct) oacc[ct][r] *= alpha[r];
    }

    // P -> LDS (C-layout -> A-layout round trip), bf16
#pragma unroll
    for (int ct = 0; ct < 4; ++ct)
#pragma unroll
      for (int r = 0; r < 4; ++r)
        sP[(w * 16 + quad * 4 + r) * 72 + ct * 16 + ln] = f2bf(sacc[ct][r]);

    // O += P @ V   (K = 64 -> 2 chunks)
#pragma unroll
    for (int kc = 0; kc < 2; ++kc) {
      const bhalf8 ap =
          *(const bhalf8*)&sP[(w * 16 + ln) * 72 + kc * 32 + quad * 8];
#pragma unroll
      for (int ct = 0; ct < 4; ++ct) {
        const bhalf8 bv =
            *(const bhalf8*)&sVt[(ct * 16 + ln) * 72 + kc * 32 + quad * 8];
        oacc[ct] =
            __builtin_amdgcn_mfma_f32_16x16x32_bf16(ap, bv, oacc[ct], 0, 0, 0);
      }
    }
  }

  // epilogue: O / l -> attO
#pragma unroll
  for (int r = 0; r < 4; ++r) {
    const float inv = 1.f / lrun[r];
    const int j = jt * 64 + w * 16 + quad * 4 + r;
    const size_t orow = ((size_t)t * ROWS + b * SS + j) * 512 + h * 64;
#pragma unroll
    for (int ct = 0; ct < 4; ++ct) attO[orow + ct * 16 + ln] = oacc[ct][r] * inv;
  }
}

// ============================================================
// Kernel 3: residual + layernorm over full 512-row
// ============================================================
__global__ __launch_bounds__(64) void ln_kernel(
    const float* __restrict__ u_emb, const float* __restrict__ f_emb,
    const float* __restrict__ attO, float* __restrict__ out) {
  const int rid = blockIdx.x;           // 0..4095
  const int t = rid >> 11, row = rid & 2047;
  const float* resid = t ? f_emb : u_emb;
  const int tid = threadIdx.x;
  const size_t base = (size_t)row * 512;
  const size_t abase = ((size_t)t * ROWS + row) * 512;

  const float4 r0 = ((const float4*)&resid[base])[tid];
  const float4 r1 = ((const float4*)&resid[base])[tid + 64];
  const float4 a0 = ((const float4*)&attO[abase])[tid];
  const float4 a1 = ((const float4*)&attO[abase])[tid + 64];
  float4 y0, y1;
  y0.x = r0.x + a0.x; y0.y = r0.y + a0.y; y0.z = r0.z + a0.z; y0.w = r0.w + a0.w;
  y1.x = r1.x + a1.x; y1.y = r1.y + a1.y; y1.z = r1.z + a1.z; y1.w = r1.w + a1.w;

  float s = y0.x + y0.y + y0.z + y0.w + y1.x + y1.y + y1.z + y1.w;
  float q = y0.x * y0.x + y0.y * y0.y + y0.z * y0.z + y0.w * y0.w +
            y1.x * y1.x + y1.y * y1.y + y1.z * y1.z + y1.w * y1.w;
#pragma unroll
  for (int off = 1; off < 64; off <<= 1) {
    s += __shfl_xor(s, off);
    q += __shfl_xor(q, off);
  }
  const float mean = s * (1.f / 512.f);
  const float var = q * (1.f / 512.f) - mean * mean;
  const float rstd = rsqrtf(var + 1e-5f);

  float4 o0, o1;
  o0.x = (y0.x - mean) * rstd; o0.y = (y0.y - mean) * rstd;
  o0.z = (y0.z - mean) * rstd; o0.w = (y0.w - mean) * rstd;
  o1.x = (y1.x - mean) * rstd; o1.y = (y1.y - mean) * rstd;
  o1.z = (y1.z - mean) * rstd; o1.w = (y1.w - mean) * rstd;
  ((float4*)&out[abase])[tid] = o0;
  ((float4*)&out[abase])[tid + 64] = o1;
}

// ============================================================
extern "C" void kernel_launch(void* const* d_in, const int* in_sizes, int n_in,
                              void* d_out, int out_size, void* d_ws,
                              size_t ws_size, hipStream_t stream) {
  (void)in_sizes; (void)n_in; (void)out_size; (void)ws_size;
  const float* u_emb = (const float*)d_in[0];
  const float* f_emb = (const float*)d_in[1];
  const float* gpe = (const float*)d_in[2];
  const float* Wq_w = (const float*)d_in[5];
  const float* Wq_b = (const float*)d_in[6];
  const float* Wkv_w = (const float*)d_in[7];
  const float* Wkv_b = (const float*)d_in[8];
  const float* Wp_w = (const float*)d_in[9];
  const float* Wp_b = (const float*)d_in[10];
  const float* Wu_w = (const float*)d_in[11];
  const float* Wu_b = (const float*)d_in[12];
  const float* Bfc = (const float*)d_in[13];
  const float* Bfp = (const float*)d_in[14];
  const float* Buc = (const float*)d_in[15];
  const float* Bup = (const float*)d_in[16];
  float* out = (float*)d_out;

  ushort_t* ws = (ushort_t*)d_ws;
  const size_t SZ = (size_t)ROWS * EMB;  // 1048576 elems
  ushort_t* qcU = ws + 0 * SZ;
  ushort_t* qpU = ws + 1 * SZ;
  ushort_t* qcF = ws + 2 * SZ;
  ushort_t* qpF = ws + 3 * SZ;
  ushort_t* khB = ws + 4 * SZ;
  ushort_t* vhB = ws + 5 * SZ;
  ushort_t* kpB = ws + 6 * SZ;
  float* attO = (float*)(ws + 7 * SZ);  // 2*2048*512 floats

  dim3 blk(256);
  dim3 g1(32, 32);
  hipLaunchKernelGGL(proj_gemm_kernel, g1, blk, 0, stream, f_emb, Wu_w, Wu_b,
                     Wq_w, Wq_b, Wkv_w, Wkv_b, Buc, Bup, Bfc, Bfp, qcU, qpU,
                     qcF, qpF, khB, vhB);
  dim3 g2(8, 32);
  hipLaunchKernelGGL(pe_gemm_kernel, g2, blk, 0, stream, gpe, Wp_w, Wp_b, kpB);
  dim3 g3(16, 16, 2);
  hipLaunchKernelGGL(attn_mfma_kernel, g3, blk, 0, stream, qcU, qpU, qcF, qpF,
                     khB, vhB, kpB, attO);
  dim3 g4(4096);
  hipLaunchKernelGGL(ln_kernel, g4, dim3(64), 0, stream, u_emb, f_emb, attO,
                     out);
}

// Round 3
// 189.403 us; speedup vs baseline: 13.9093x; 1.2109x over previous
//
#include <hip/hip_runtime.h>
#include <math.h>

#define EMB 512
#define NH 8
#define HD 64
#define BB 2
#define SS 1024
#define ROWS (BB * SS) /* 2048 */

typedef __attribute__((ext_vector_type(8))) short bhalf8;
typedef __attribute__((ext_vector_type(4))) float f32x4;
typedef __attribute__((ext_vector_type(8))) unsigned short us8;
typedef unsigned short ushort_t;

__device__ __forceinline__ unsigned short f2bf(float x) {
  unsigned u = __float_as_uint(x);
  u = (u + 0x7FFFu + ((u >> 16) & 1u)) >> 16;
  return (unsigned short)u;
}

__device__ __forceinline__ float fast_tanh(float x) {
  x = fminf(15.f, fmaxf(-15.f, x));
  const float e = __expf(2.f * x);
  return (e - 1.f) / (e + 1.f);
}

// ============================================================
// Convert fp32 -> bf16 (8 elems/thread)
// ============================================================
__global__ __launch_bounds__(256) void convf2b_kernel(
    const float* __restrict__ src, ushort_t* __restrict__ dst, int n) {
  const int i = (blockIdx.x * 256 + threadIdx.x) * 8;
  if (i >= n) return;
  const float4 a = *(const float4*)&src[i];
  const float4 b = *(const float4*)&src[i + 4];
  us8 o;
  o[0] = f2bf(a.x); o[1] = f2bf(a.y); o[2] = f2bf(a.z); o[3] = f2bf(a.w);
  o[4] = f2bf(b.x); o[5] = f2bf(b.y); o[6] = f2bf(b.z); o[7] = f2bf(b.w);
  *(us8*)&dst[i] = o;
}

// ============================================================
// Weight transpose + convert: W[K][N] fp32 -> Wt[N][K] bf16
// z: 0=Wu, 1=Wq, 2=Wkv, 3=Wp. 64x64 tiles via LDS.
// ============================================================
__global__ __launch_bounds__(256) void wtrans_kernel(
    const float* __restrict__ Wu, const float* __restrict__ Wq,
    const float* __restrict__ Wkv, const float* __restrict__ Wp,
    ushort_t* __restrict__ WtAll, ushort_t* __restrict__ WpT) {
  const int z = blockIdx.z;
  const float* src;
  ushort_t* dst;
  int K, N;
  if (z == 0) { src = Wu;  dst = WtAll;              K = 512; N = 512; }
  else if (z == 1) { src = Wq;  dst = WtAll + 512 * 512;  K = 512; N = 512; }
  else if (z == 2) { src = Wkv; dst = WtAll + 1024 * 512; K = 512; N = 1024; }
  else { src = Wp;  dst = WpT;               K = 128; N = 512; }
  const int n0 = blockIdx.x * 64, k0 = blockIdx.y * 64;
  if (n0 >= N || k0 >= K) return;
  const int tid = threadIdx.x;

  __shared__ float sT[64 * 65];
#pragma unroll
  for (int i = 0; i < 4; ++i) {
    const int idx = i * 256 + tid;
    const int r = idx >> 4, c4 = (idx & 15) * 4;
    const float4 v = *(const float4*)&src[(size_t)(k0 + r) * N + n0 + c4];
    sT[(c4 + 0) * 65 + r] = v.x;
    sT[(c4 + 1) * 65 + r] = v.y;
    sT[(c4 + 2) * 65 + r] = v.z;
    sT[(c4 + 3) * 65 + r] = v.w;
  }
  __syncthreads();
#pragma unroll
  for (int i = 0; i < 2; ++i) {
    const int idx = i * 256 + tid;
    const int rr = idx >> 3, ch = (idx & 7) * 8;
    us8 o;
#pragma unroll
    for (int jj = 0; jj < 8; ++jj) o[jj] = f2bf(sT[rr * 65 + ch + jj]);
    *(us8*)&dst[(size_t)(n0 + rr) * K + k0 + ch] = o;
  }
}

// ============================================================
// proj MFMA GEMM: D[m][n] = sum_k A16[m][k] * Wt[n][k]
// M=N=2048, K=512. 128x128 tile, BK=64, 4 waves (2x2) of 64x64.
// Epilogue by n-group: [0,512)=qU, [512,1024)=qF, [1024,1536)=kh,
// [1536,2048)=vh, fused bias+tanh -> bf16.
// ============================================================
__global__ __launch_bounds__(256) void proj_mfma_kernel(
    const ushort_t* __restrict__ A16, const ushort_t* __restrict__ Wt,
    const float* __restrict__ Wu_b, const float* __restrict__ Wq_b,
    const float* __restrict__ Wkv_b, const float* __restrict__ Buc,
    const float* __restrict__ Bup, const float* __restrict__ Bfc,
    const float* __restrict__ Bfp, ushort_t* __restrict__ qcU,
    ushort_t* __restrict__ qpU, ushort_t* __restrict__ qcF,
    ushort_t* __restrict__ qpF, ushort_t* __restrict__ khB,
    ushort_t* __restrict__ vhB) {
  const int nb = blockIdx.x * 128, mb = blockIdx.y * 128;
  const int tid = threadIdx.x;
  const int w = tid >> 6, lane = tid & 63;
  const int ln = lane & 15, quad = lane >> 4;
  const int wm = (w >> 1) * 64, wn = (w & 1) * 64;

  __shared__ __align__(16) ushort_t sA[128 * 72];
  __shared__ __align__(16) ushort_t sB[128 * 72];

  f32x4 acc[4][4];
#pragma unroll
  for (int rt = 0; rt < 4; ++rt)
#pragma unroll
    for (int ct = 0; ct < 4; ++ct) acc[rt][ct] = (f32x4){0.f, 0.f, 0.f, 0.f};

  for (int k0 = 0; k0 < 512; k0 += 64) {
    __syncthreads();
#pragma unroll
    for (int i = 0; i < 4; ++i) {
      const int idx = i * 256 + tid;
      const int r = idx >> 3, ch = (idx & 7) * 8;
      *(uint4*)&sA[r * 72 + ch] =
          *(const uint4*)&A16[(size_t)(mb + r) * 512 + k0 + ch];
      *(uint4*)&sB[r * 72 + ch] =
          *(const uint4*)&Wt[(size_t)(nb + r) * 512 + k0 + ch];
    }
    __syncthreads();
#pragma unroll
    for (int kc = 0; kc < 2; ++kc) {
      bhalf8 af[4], bf_[4];
#pragma unroll
      for (int rt = 0; rt < 4; ++rt)
        af[rt] =
            *(const bhalf8*)&sA[(wm + rt * 16 + ln) * 72 + kc * 32 + quad * 8];
#pragma unroll
      for (int ct = 0; ct < 4; ++ct)
        bf_[ct] =
            *(const bhalf8*)&sB[(wn + ct * 16 + ln) * 72 + kc * 32 + quad * 8];
#pragma unroll
      for (int rt = 0; rt < 4; ++rt)
#pragma unroll
        for (int ct = 0; ct < 4; ++ct)
          acc[rt][ct] = __builtin_amdgcn_mfma_f32_16x16x32_bf16(
              af[rt], bf_[ct], acc[rt][ct], 0, 0, 0);
    }
  }

  // epilogue (block-uniform n-group; 128-tile never straddles a 512 boundary)
  if (nb < 512) {
#pragma unroll
    for (int ct = 0; ct < 4; ++ct) {
      const int n = nb + wn + ct * 16 + ln;
      const float wb = Wu_b[n], bc = Buc[n], bp = Bup[n];
#pragma unroll
      for (int rt = 0; rt < 4; ++rt)
#pragma unroll
        for (int r = 0; r < 4; ++r) {
          const int m = mb + wm + rt * 16 + quad * 4 + r;
          const float v = acc[rt][ct][r] + wb;
          qcU[(size_t)m * 512 + n] = f2bf(fast_tanh(v + bc));
          qpU[(size_t)m * 512 + n] = f2bf(fast_tanh(v + bp));
        }
    }
  } else if (nb < 1024) {
#pragma unroll
    for (int ct = 0; ct < 4; ++ct) {
      const int n = nb + wn + ct * 16 + ln;
      const int nn = n - 512;
      const float wb = Wq_b[nn], bc = Bfc[nn], bp = Bfp[nn];
#pragma unroll
      for (int rt = 0; rt < 4; ++rt)
#pragma unroll
        for (int r = 0; r < 4; ++r) {
          const int m = mb + wm + rt * 16 + quad * 4 + r;
          const float v = acc[rt][ct][r] + wb;
          qcF[(size_t)m * 512 + nn] = f2bf(fast_tanh(v + bc));
          qpF[(size_t)m * 512 + nn] = f2bf(fast_tanh(v + bp));
        }
    }
  } else if (nb < 1536) {
#pragma unroll
    for (int ct = 0; ct < 4; ++ct) {
      const int n = nb + wn + ct * 16 + ln;
      const int nn = n - 1024;
      const float wb = Wkv_b[nn];
#pragma unroll
      for (int rt = 0; rt < 4; ++rt)
#pragma unroll
        for (int r = 0; r < 4; ++r) {
          const int m = mb + wm + rt * 16 + quad * 4 + r;
          khB[(size_t)m * 512 + nn] = f2bf(fast_tanh(acc[rt][ct][r] + wb));
        }
    }
  } else {
#pragma unroll
    for (int ct = 0; ct < 4; ++ct) {
      const int n = nb + wn + ct * 16 + ln;
      const float wb = Wkv_b[n - 1024];
      const int nn = n - 1536;
#pragma unroll
      for (int rt = 0; rt < 4; ++rt)
#pragma unroll
        for (int r = 0; r < 4; ++r) {
          const int m = mb + wm + rt * 16 + quad * 4 + r;
          vhB[(size_t)m * 512 + nn] = f2bf(fast_tanh(acc[rt][ct][r] + wb));
        }
    }
  }
}

// ============================================================
// pe MFMA GEMM: kp[m][n] = tanh(sum_k gpe16[m][k]*WpT[n][k] + Wp_b[n])
// M=2048, N=512, K=128.
// ============================================================
__global__ __launch_bounds__(256) void pe_mfma_kernel(
    const ushort_t* __restrict__ A16, const ushort_t* __restrict__ WpT,
    const float* __restrict__ Wp_b, ushort_t* __restrict__ kpB) {
  const int nb = blockIdx.x * 128, mb = blockIdx.y * 128;
  const int tid = threadIdx.x;
  const int w = tid >> 6, lane = tid & 63;
  const int ln = lane & 15, quad = lane >> 4;
  const int wm = (w >> 1) * 64, wn = (w & 1) * 64;

  __shared__ __align__(16) ushort_t sA[128 * 72];
  __shared__ __align__(16) ushort_t sB[128 * 72];

  f32x4 acc[4][4];
#pragma unroll
  for (int rt = 0; rt < 4; ++rt)
#pragma unroll
    for (int ct = 0; ct < 4; ++ct) acc[rt][ct] = (f32x4){0.f, 0.f, 0.f, 0.f};

#pragma unroll
  for (int k0 = 0; k0 < 128; k0 += 64) {
    __syncthreads();
#pragma unroll
    for (int i = 0; i < 4; ++i) {
      const int idx = i * 256 + tid;
      const int r = idx >> 3, ch = (idx & 7) * 8;
      *(uint4*)&sA[r * 72 + ch] =
          *(const uint4*)&A16[(size_t)(mb + r) * 128 + k0 + ch];
      *(uint4*)&sB[r * 72 + ch] =
          *(const uint4*)&WpT[(size_t)(nb + r) * 128 + k0 + ch];
    }
    __syncthreads();
#pragma unroll
    for (int kc = 0; kc < 2; ++kc) {
      bhalf8 af[4], bf_[4];
#pragma unroll
      for (int rt = 0; rt < 4; ++rt)
        af[rt] =
            *(const bhalf8*)&sA[(wm + rt * 16 + ln) * 72 + kc * 32 + quad * 8];
#pragma unroll
      for (int ct = 0; ct < 4; ++ct)
        bf_[ct] =
            *(const bhalf8*)&sB[(wn + ct * 16 + ln) * 72 + kc * 32 + quad * 8];
#pragma unroll
      for (int rt = 0; rt < 4; ++rt)
#pragma unroll
        for (int ct = 0; ct < 4; ++ct)
          acc[rt][ct] = __builtin_amdgcn_mfma_f32_16x16x32_bf16(
              af[rt], bf_[ct], acc[rt][ct], 0, 0, 0);
    }
  }

#pragma unroll
  for (int ct = 0; ct < 4; ++ct) {
    const int n = nb + wn + ct * 16 + ln;
    const float wb = Wp_b[n];
#pragma unroll
    for (int rt = 0; rt < 4; ++rt)
#pragma unroll
      for (int r = 0; r < 4; ++r) {
        const int m = mb + wm + rt * 16 + quad * 4 + r;
        kpB[(size_t)m * 512 + n] = f2bf(fast_tanh(acc[rt][ct][r] + wb));
      }
  }
}

// ============================================================
// Kernel 2: flash-style MFMA attention (unchanged from round 2).
// ============================================================
__global__ __launch_bounds__(256, 3) void attn_mfma_kernel(
    const ushort_t* __restrict__ qcU, const ushort_t* __restrict__ qpU,
    const ushort_t* __restrict__ qcF, const ushort_t* __restrict__ qpF,
    const ushort_t* __restrict__ khB, const ushort_t* __restrict__ vhB,
    const ushort_t* __restrict__ kpB, float* __restrict__ attO) {
  const int jt = 15 - (int)blockIdx.x;  // heavy tiles first
  const int h = blockIdx.y & 7, b = blockIdx.y >> 3;
  const int t = blockIdx.z;
  const int tid = threadIdx.x;
  const int w = tid >> 6;
  const int lane = tid & 63;
  const int ln = lane & 15, quad = lane >> 4;

  __shared__ __align__(16) ushort_t sQ2[64 * 136];
  __shared__ __align__(16) ushort_t sK2[64 * 136];
  __shared__ __align__(16) ushort_t sVt[64 * 72];
  __shared__ __align__(16) ushort_t sP[64 * 72];

  const ushort_t* qcS = t ? qcF : qcU;
  const ushort_t* qpS = t ? qpF : qpU;

#pragma unroll
  for (int i = 0; i < 2; ++i) {
    const int idx = tid + i * 256;
    const int r = idx >> 3, c = idx & 7;
    const int j = jt * 64 + r;
    const size_t qrow = (size_t)(b * SS + j);
    *(uint4*)&sQ2[r * 136 + c * 8] =
        *(const uint4*)&qcS[qrow * 512 + h * 64 + c * 8];
    uint4 qp;
    if (b == 0) {
      if (j == SS - 1)
        qp = make_uint4(0u, 0u, 0u, 0u);
      else
        qp = *(const uint4*)&qpS[(qrow + 1) * 512 + h * 64 + c * 8];
    } else {
      qp = *(const uint4*)&qpS[qrow * 512 + h * 64 + c * 8];
    }
    *(uint4*)&sQ2[r * 136 + 64 + c * 8] = qp;
  }
  __syncthreads();

  bhalf8 aq[4];
#pragma unroll
  for (int kc = 0; kc < 4; ++kc)
    aq[kc] = *(const bhalf8*)&sQ2[(w * 16 + ln) * 136 + kc * 32 + quad * 8];

  f32x4 oacc[4];
#pragma unroll
  for (int ct = 0; ct < 4; ++ct) oacc[ct] = (f32x4){0.f, 0.f, 0.f, 0.f};
  float mrun[4], lrun[4];
#pragma unroll
  for (int r = 0; r < 4; ++r) { mrun[r] = -1e30f; lrun[r] = 0.f; }

  for (int kt = 0; kt <= jt; ++kt) {
    __syncthreads();
#pragma unroll
    for (int i = 0; i < 2; ++i) {
      const int idx = tid + i * 256;
      const int r = idx >> 3, c = idx & 7;
      const size_t krow = (size_t)(b * SS + kt * 64 + r);
      *(uint4*)&sK2[r * 136 + c * 8] =
          *(const uint4*)&khB[krow * 512 + h * 64 + c * 8];
      *(uint4*)&sK2[r * 136 + 64 + c * 8] =
          *(const uint4*)&kpB[krow * 512 + h * 64 + c * 8];
    }
#pragma unroll
    for (int i = 0; i < 2; ++i) {
      const int idx = tid + i * 256;
      const int r = idx >> 3, dq = idx & 7;
      const size_t vrow = (size_t)(b * SS + kt * 64 + r);
      const uint4 vv = *(const uint4*)&vhB[vrow * 512 + h * 64 + dq * 8];
      unsigned va[4] = {vv.x, vv.y, vv.z, vv.w};
#pragma unroll
      for (int q2 = 0; q2 < 4; ++q2) {
        sVt[(dq * 8 + q2 * 2 + 0) * 72 + r] = (ushort_t)(va[q2] & 0xffffu);
        sVt[(dq * 8 + q2 * 2 + 1) * 72 + r] = (ushort_t)(va[q2] >> 16);
      }
    }
    __syncthreads();

    f32x4 sacc[4];
#pragma unroll
    for (int ct = 0; ct < 4; ++ct) {
      sacc[ct] = (f32x4){0.f, 0.f, 0.f, 0.f};
#pragma unroll
      for (int kc = 0; kc < 4; ++kc) {
        const bhalf8 bk =
            *(const bhalf8*)&sK2[(ct * 16 + ln) * 136 + kc * 32 + quad * 8];
        sacc[ct] = __builtin_amdgcn_mfma_f32_16x16x32_bf16(aq[kc], bk,
                                                           sacc[ct], 0, 0, 0);
      }
    }

    const bool diag = (kt == jt);
#pragma unroll
    for (int ct = 0; ct < 4; ++ct)
#pragma unroll
      for (int r = 0; r < 4; ++r) {
        float v = sacc[ct][r] * 0.125f;
        if (diag && (ct * 16 + ln > w * 16 + quad * 4 + r)) v = -1e30f;
        sacc[ct][r] = v;
      }

    float mnew[4], alpha[4], psum[4];
#pragma unroll
    for (int r = 0; r < 4; ++r) {
      float v = fmaxf(fmaxf(sacc[0][r], sacc[1][r]),
                      fmaxf(sacc[2][r], sacc[3][r]));
      v = fmaxf(v, __shfl_xor(v, 1));
      v = fmaxf(v, __shfl_xor(v, 2));
      v = fmaxf(v, __shfl_xor(v, 4));
      v = fmaxf(v, __shfl_xor(v, 8));
      mnew[r] = fmaxf(mrun[r], v);
      alpha[r] = __expf(mrun[r] - mnew[r]);
      mrun[r] = mnew[r];
      psum[r] = 0.f;
    }
#pragma unroll
    for (int ct = 0; ct < 4; ++ct)
#pragma unroll
      for (int r = 0; r < 4; ++r) {
        const float p = __expf(sacc[ct][r] - mnew[r]);
        sacc[ct][r] = p;
        psum[r] += p;
      }
#pragma unroll
    for (int r = 0; r < 4; ++r) {
      float s = psum[r];
      s += __shfl_xor(s, 1);
      s += __shfl_xor(s, 2);
      s += __shfl_xor(s, 4);
      s += __shfl_xor(s, 8);
      lrun[r] = lrun[r] * alpha[r] + s;
#pragma unroll
      for (int ct = 0; ct < 4; ++ct) oacc[ct][r] *= alpha[r];
    }

#pragma unroll
    for (int ct = 0; ct < 4; ++ct)
#pragma unroll
      for (int r = 0; r < 4; ++r)
        sP[(w * 16 + quad * 4 + r) * 72 + ct * 16 + ln] = f2bf(sacc[ct][r]);

#pragma unroll
    for (int kc = 0; kc < 2; ++kc) {
      const bhalf8 ap =
          *(const bhalf8*)&sP[(w * 16 + ln) * 72 + kc * 32 + quad * 8];
#pragma unroll
      for (int ct = 0; ct < 4; ++ct) {
        const bhalf8 bv =
            *(const bhalf8*)&sVt[(ct * 16 + ln) * 72 + kc * 32 + quad * 8];
        oacc[ct] =
            __builtin_amdgcn_mfma_f32_16x16x32_bf16(ap, bv, oacc[ct], 0, 0, 0);
      }
    }
  }

#pragma unroll
  for (int r = 0; r < 4; ++r) {
    const float inv = 1.f / lrun[r];
    const int j = jt * 64 + w * 16 + quad * 4 + r;
    const size_t orow = ((size_t)t * ROWS + b * SS + j) * 512 + h * 64;
#pragma unroll
    for (int ct = 0; ct < 4; ++ct)
      attO[orow + ct * 16 + ln] = oacc[ct][r] * inv;
  }
}

// ============================================================
// Kernel 3: residual + layernorm (unchanged)
// ============================================================
__global__ __launch_bounds__(64) void ln_kernel(
    const float* __restrict__ u_emb, const float* __restrict__ f_emb,
    const float* __restrict__ attO, float* __restrict__ out) {
  const int rid = blockIdx.x;
  const int t = rid >> 11, row = rid & 2047;
  const float* resid = t ? f_emb : u_emb;
  const int tid = threadIdx.x;
  const size_t base = (size_t)row * 512;
  const size_t abase = ((size_t)t * ROWS + row) * 512;

  const float4 r0 = ((const float4*)&resid[base])[tid];
  const float4 r1 = ((const float4*)&resid[base])[tid + 64];
  const float4 a0 = ((const float4*)&attO[abase])[tid];
  const float4 a1 = ((const float4*)&attO[abase])[tid + 64];
  float4 y0, y1;
  y0.x = r0.x + a0.x; y0.y = r0.y + a0.y; y0.z = r0.z + a0.z; y0.w = r0.w + a0.w;
  y1.x = r1.x + a1.x; y1.y = r1.y + a1.y; y1.z = r1.z + a1.z; y1.w = r1.w + a1.w;

  float s = y0.x + y0.y + y0.z + y0.w + y1.x + y1.y + y1.z + y1.w;
  float q = y0.x * y0.x + y0.y * y0.y + y0.z * y0.z + y0.w * y0.w +
            y1.x * y1.x + y1.y * y1.y + y1.z * y1.z + y1.w * y1.w;
#pragma unroll
  for (int off = 1; off < 64; off <<= 1) {
    s += __shfl_xor(s, off);
    q += __shfl_xor(q, off);
  }
  const float mean = s * (1.f / 512.f);
  const float var = q * (1.f / 512.f) - mean * mean;
  const float rstd = rsqrtf(var + 1e-5f);

  float4 o0, o1;
  o0.x = (y0.x - mean) * rstd; o0.y = (y0.y - mean) * rstd;
  o0.z = (y0.z - mean) * rstd; o0.w = (y0.w - mean) * rstd;
  o1.x = (y1.x - mean) * rstd; o1.y = (y1.y - mean) * rstd;
  o1.z = (y1.z - mean) * rstd; o1.w = (y1.w - mean) * rstd;
  ((float4*)&out[abase])[tid] = o0;
  ((float4*)&out[abase])[tid + 64] = o1;
}

// ============================================================
extern "C" void kernel_launch(void* const* d_in, const int* in_sizes, int n_in,
                              void* d_out, int out_size, void* d_ws,
                              size_t ws_size, hipStream_t stream) {
  (void)in_sizes; (void)n_in; (void)out_size; (void)ws_size;
  const float* u_emb = (const float*)d_in[0];
  const float* f_emb = (const float*)d_in[1];
  const float* gpe = (const float*)d_in[2];
  const float* Wq_w = (const float*)d_in[5];
  const float* Wq_b = (const float*)d_in[6];
  const float* Wkv_w = (const float*)d_in[7];
  const float* Wkv_b = (const float*)d_in[8];
  const float* Wp_w = (const float*)d_in[9];
  const float* Wp_b = (const float*)d_in[10];
  const float* Wu_w = (const float*)d_in[11];
  const float* Wu_b = (const float*)d_in[12];
  const float* Bfc = (const float*)d_in[13];
  const float* Bfp = (const float*)d_in[14];
  const float* Buc = (const float*)d_in[15];
  const float* Bup = (const float*)d_in[16];
  float* out = (float*)d_out;

  ushort_t* ws = (ushort_t*)d_ws;
  const size_t SZ = (size_t)ROWS * EMB;  // 1048576 elems
  ushort_t* qcU = ws + 0 * SZ;
  ushort_t* qpU = ws + 1 * SZ;
  ushort_t* qcF = ws + 2 * SZ;
  ushort_t* qpF = ws + 3 * SZ;
  ushort_t* khB = ws + 4 * SZ;
  ushort_t* vhB = ws + 5 * SZ;
  ushort_t* kpB = ws + 6 * SZ;
  float* attO = (float*)(ws + 7 * SZ);  // 2*2048*512 floats = 4*SZ ushorts
  // overlay (consumed before attn writes attO):
  ushort_t* ov = ws + 7 * SZ;
  ushort_t* f16emb = ov;                       // SZ
  ushort_t* gpe16 = ov + SZ;                   // ROWS*128 = 262144
  ushort_t* WtAll = ov + SZ + 262144;          // 2048*512 = SZ
  ushort_t* WpT = ov + 2 * SZ + 262144;        // 512*128 = 65536

  dim3 blk(256);
  hipLaunchKernelGGL(convf2b_kernel, dim3(512), blk, 0, stream, f_emb, f16emb,
                     (int)SZ);
  hipLaunchKernelGGL(convf2b_kernel, dim3(128), blk, 0, stream, gpe, gpe16,
                     ROWS * 128);
  hipLaunchKernelGGL(wtrans_kernel, dim3(16, 8, 4), blk, 0, stream, Wu_w, Wq_w,
                     Wkv_w, Wp_w, WtAll, WpT);
  hipLaunchKernelGGL(proj_mfma_kernel, dim3(16, 16), blk, 0, stream, f16emb,
                     WtAll, Wu_b, Wq_b, Wkv_b, Buc, Bup, Bfc, Bfp, qcU, qpU,
                     qcF, qpF, khB, vhB);
  hipLaunchKernelGGL(pe_mfma_kernel, dim3(4, 16), blk, 0, stream, gpe16, WpT,
                     Wp_b, kpB);
  dim3 g3(16, 16, 2);
  hipLaunchKernelGGL(attn_mfma_kernel, g3, blk, 0, stream, qcU, qpU, qcF, qpF,
                     khB, vhB, kpB, attO);
  dim3 g4(4096);
  hipLaunchKernelGGL(ln_kernel, g4, dim3(64), 0, stream, u_emb, f_emb, attO,
                     out);
}